// Round 1
// baseline (3054.636 us; speedup 1.0000x reference)
//
#include <hip/hip_runtime.h>
#include <math.h>

#define NN 12288
#define DD 128
#define EPSF 1e-7f
#define MAXNORM (1.0f - 1e-3f)

#define TI 64
#define TJ 64

// ---------------- Kernel 1: per-row prep ----------------
// x_tan = atanh(clip(||x||,EPS,1-EPS)) * x / clip(...)
// wh1 = x_tan . a[:D], wh2 = x_tan . a[D:]
// store xt (fp32), wh1, wh2, e^{wh1}, e^{0.2wh1}, e^{wh2}, e^{0.2wh2}
__global__ __launch_bounds__(128) void prep_kernel(
    const float* __restrict__ x, const float* __restrict__ a,
    float* __restrict__ xt,
    float* __restrict__ wh1, float* __restrict__ wh2,
    float* __restrict__ ew1, float* __restrict__ ew1b,
    float* __restrict__ ey,  float* __restrict__ ez)
{
    const int r = blockIdx.x;
    const int t = threadIdx.x;
    const float xv = x[r * DD + t];
    const float a1 = a[t];
    const float a2 = a[DD + t];
    float s0 = xv * xv;
    float s1 = xv * a1;
    float s2 = xv * a2;
    #pragma unroll
    for (int o = 32; o > 0; o >>= 1) {
        s0 += __shfl_xor(s0, o);
        s1 += __shfl_xor(s1, o);
        s2 += __shfl_xor(s2, o);
    }
    __shared__ float red[6];
    const int w = t >> 6;
    if ((t & 63) == 0) { red[w * 3 + 0] = s0; red[w * 3 + 1] = s1; red[w * 3 + 2] = s2; }
    __syncthreads();
    const float sumsq = red[0] + red[3];
    const float d1    = red[1] + red[4];
    const float d2    = red[2] + red[5];
    const float nraw  = sqrtf(sumsq);
    const float nrm   = fminf(fmaxf(nraw, EPSF), 1.0f - EPSF);
    const float scale = atanhf(nrm) / nrm;
    xt[r * DD + t] = xv * scale;
    if (t == 0) {
        const float w1 = scale * d1;
        const float w2 = scale * d2;
        wh1[r] = w1; wh2[r] = w2;
        ew1[r]  = expf(w1);
        ew1b[r] = expf(0.2f * w1);
        ey[r]   = expf(w2);
        ez[r]   = expf(0.2f * w2);
    }
}

// ---------------- Kernel 2: masked rank-1-score attention ----------------
// out_i = proj(expmap0( (sum_j p_ij * xt_j) / (sum_j p_ij) ))
// p_ij = adj_ij ? ((wh1_i+wh2_j > 0) ? ew1_i*ey_j : ew1b_i*ez_j) : 0
__global__ __launch_bounds__(256) void attn_kernel(
    const int* __restrict__ adj,
    const float* __restrict__ xt,
    const float* __restrict__ wh1,
    const float* __restrict__ ew1, const float* __restrict__ ew1b,
    const float* __restrict__ wh2,
    const float* __restrict__ ey,  const float* __restrict__ ez,
    float* __restrict__ out)
{
    __shared__ float xt_lds[TJ * DD];          // 32 KB, row-major [j][d]
    __shared__ float p_lds[TI * (TJ + 1)];     // padded stride 65 -> conflict-free
    __shared__ float is_wh1[TI], is_e1[TI], is_e1b[TI];

    const int t  = threadIdx.x;
    const int i0 = blockIdx.x * TI;
    const int dg = t & 15;          // 0..15 : d-chunk owner
    const int ig = t >> 4;          // 0..15 : i-group owner (4 rows each)
    const int d0a = dg * 4;         // floats [d0a, d0a+4)
    const int d0b = 64 + dg * 4;    // floats [d0b, d0b+4)
    const int jw = t & 63;          // phase A/B lane -> j offset
    const int wv = t >> 6;          // wave id 0..3
    const int ibase = ig * 4;

    if (t < TI) {
        is_wh1[t] = wh1[i0 + t];
        is_e1[t]  = ew1[i0 + t];
        is_e1b[t] = ew1b[i0 + t];
    }

    float acc[4][8];
    float lsum[4];
    #pragma unroll
    for (int k = 0; k < 4; ++k) {
        lsum[k] = 0.0f;
        #pragma unroll
        for (int m = 0; m < 8; ++m) acc[k][m] = 0.0f;
    }

    for (int j0 = 0; j0 < NN; j0 += TJ) {
        __syncthreads();   // previous phase-C reads done before we overwrite LDS

        // ---- phase A: stage xt tile (TJ x DD floats = 2048 float4) ----
        {
            const float4* src = (const float4*)(xt + j0 * DD);
            float4* dst = (float4*)xt_lds;
            #pragma unroll
            for (int m = 0; m < 8; ++m) dst[m * 256 + t] = src[m * 256 + t];
        }

        // ---- phase B: compute p tile; adj read once, coalesced ----
        {
            const float w2j = wh2[j0 + jw];
            const float eyj = ey[j0 + jw];
            const float ezj = ez[j0 + jw];
            const int base = (i0 + wv) * NN + j0 + jw;
            #pragma unroll
            for (int k = 0; k < 16; ++k) {
                const int il = wv + 4 * k;                // 0..63
                const int aij = adj[base + 4 * k * NN];
                float p = 0.0f;
                if (aij > 0) {
                    const bool cpos = (is_wh1[il] + w2j) > 0.0f;
                    p = cpos ? is_e1[il] * eyj : is_e1b[il] * ezj;
                }
                p_lds[il * (TJ + 1) + jw] = p;
            }
        }
        __syncthreads();

        // ---- phase C: accumulate 4 rows x 8 cols per thread ----
        const int pb = ibase * (TJ + 1);
        #pragma unroll 4
        for (int j = 0; j < TJ; ++j) {
            const float4 xa = *(const float4*)&xt_lds[j * DD + d0a];
            const float4 xb = *(const float4*)&xt_lds[j * DD + d0b];
            #pragma unroll
            for (int k = 0; k < 4; ++k) {
                const float p = p_lds[pb + k * (TJ + 1) + j];
                acc[k][0] += p * xa.x; acc[k][1] += p * xa.y;
                acc[k][2] += p * xa.z; acc[k][3] += p * xa.w;
                acc[k][4] += p * xb.x; acc[k][5] += p * xb.y;
                acc[k][6] += p * xb.z; acc[k][7] += p * xb.w;
                lsum[k] += p;
            }
        }
    }

    // ---- epilogue: normalize, expmap0, proj ----
    #pragma unroll
    for (int k = 0; k < 4; ++k) {
        const float linv = 1.0f / lsum[k];
        float v[8];
        float ss = 0.0f;
        #pragma unroll
        for (int m = 0; m < 8; ++m) { v[m] = acc[k][m] * linv; ss += v[m] * v[m]; }
        // reduce over the 16 dg-lanes (aligned 16-lane groups within the wave)
        #pragma unroll
        for (int o = 1; o < 16; o <<= 1) ss += __shfl_xor(ss, o);
        const float nraw = sqrtf(ss);
        const float nv   = fmaxf(nraw, EPSF);        // expmap0 clip (lower only)
        const float th   = tanhf(nv);
        const float ysc  = th / nv;                  // y = ysc * v
        const float nyr  = ysc * nraw;               // ||y||
        const float ny   = fmaxf(nyr, EPSF);         // proj clip (lower only)
        const float psc  = (ny > MAXNORM) ? (MAXNORM / ny) : 1.0f;
        const float os   = ysc * psc;
        const int i = i0 + ibase + k;
        float4 o1, o2;
        o1.x = v[0] * os; o1.y = v[1] * os; o1.z = v[2] * os; o1.w = v[3] * os;
        o2.x = v[4] * os; o2.y = v[5] * os; o2.z = v[6] * os; o2.w = v[7] * os;
        *(float4*)&out[i * DD + d0a] = o1;
        *(float4*)&out[i * DD + d0b] = o2;
    }
}

extern "C" void kernel_launch(void* const* d_in, const int* in_sizes, int n_in,
                              void* d_out, int out_size, void* d_ws, size_t ws_size,
                              hipStream_t stream) {
    const float* x   = (const float*)d_in[0];
    const int*   adj = (const int*)d_in[1];
    const float* a   = (const float*)d_in[2];
    float* out = (float*)d_out;

    char* ws = (char*)d_ws;
    float* xt   = (float*)ws;                          ws += (size_t)NN * DD * sizeof(float);
    float* wh1  = (float*)ws;                          ws += NN * sizeof(float);
    float* wh2  = (float*)ws;                          ws += NN * sizeof(float);
    float* ew1  = (float*)ws;                          ws += NN * sizeof(float);
    float* ew1b = (float*)ws;                          ws += NN * sizeof(float);
    float* eyv  = (float*)ws;                          ws += NN * sizeof(float);
    float* ezv  = (float*)ws;                          ws += NN * sizeof(float);

    prep_kernel<<<NN, 128, 0, stream>>>(x, a, xt, wh1, wh2, ew1, ew1b, eyv, ezv);
    attn_kernel<<<NN / TI, 256, 0, stream>>>(adj, xt, wh1, ew1, ew1b, wh2, eyv, ezv, out);
}

// Round 2
// 1024.204 us; speedup vs baseline: 2.9824x; 2.9824x over previous
//
#include <hip/hip_runtime.h>
#include <math.h>

#define NN 12288
#define DD 128
#define EPSF 1e-7f
#define MAXNORM (1.0f - 1e-3f)

#define TI 32
#define TJ 64
#define LDP 72   // padded LDS row stride in bf16 elements (144 B, multiple of 16 B)

typedef __attribute__((ext_vector_type(8))) short short8_t;
typedef __attribute__((ext_vector_type(4))) float float4_t;
typedef unsigned short ushort_t;

__device__ __forceinline__ unsigned short f2bf(float f) {
    unsigned int u = __builtin_bit_cast(unsigned int, f);
    unsigned int r = u + 0x7FFFu + ((u >> 16) & 1u);
    return (unsigned short)(r >> 16);
}

// ---------------- Kernel 1: per-row prep ----------------
// xtb[j][d] = bf16(logmap0(x)[j][d]); wh1/wh2 scalars; exp tables.
__global__ __launch_bounds__(128) void prep_kernel(
    const float* __restrict__ x, const float* __restrict__ a,
    ushort_t* __restrict__ xtb,
    float* __restrict__ wh1, float* __restrict__ wh2,
    float* __restrict__ e1, float* __restrict__ e1b,
    float* __restrict__ ey, float* __restrict__ ez)
{
    const int r = blockIdx.x;
    const int t = threadIdx.x;
    const float xv = x[r * DD + t];
    const float a1 = a[t];
    const float a2 = a[DD + t];
    float s0 = xv * xv, s1 = xv * a1, s2 = xv * a2;
    #pragma unroll
    for (int o = 32; o > 0; o >>= 1) {
        s0 += __shfl_xor(s0, o);
        s1 += __shfl_xor(s1, o);
        s2 += __shfl_xor(s2, o);
    }
    __shared__ float red[6];
    const int w = t >> 6;
    if ((t & 63) == 0) { red[w * 3 + 0] = s0; red[w * 3 + 1] = s1; red[w * 3 + 2] = s2; }
    __syncthreads();
    const float sumsq = red[0] + red[3];
    const float d1    = red[1] + red[4];
    const float d2    = red[2] + red[5];
    const float nraw  = sqrtf(sumsq);
    const float nrm   = fminf(fmaxf(nraw, EPSF), 1.0f - EPSF);
    const float scale = atanhf(nrm) / nrm;
    xtb[(size_t)r * DD + t] = f2bf(xv * scale);
    if (t == 0) {
        const float w1 = scale * d1;
        const float w2 = scale * d2;
        wh1[r] = w1; wh2[r] = w2;
        e1[r]  = expf(w1);
        e1b[r] = expf(0.2f * w1);
        ey[r]  = expf(w2);
        ez[r]  = expf(0.2f * w2);
    }
}

// ---------------- Kernel 2: transpose xtb -> xtT[d][j] ----------------
__global__ __launch_bounds__(256) void transpose_kernel(
    const ushort_t* __restrict__ xtb, ushort_t* __restrict__ xtT)
{
    __shared__ ushort_t tile[64][65];
    const int j0 = blockIdx.x * 64;
    const int d0 = blockIdx.y * 64;
    const int t = threadIdx.x;
    const int c = t & 63, r4 = t >> 6;
    #pragma unroll
    for (int k = 0; k < 16; ++k) {
        const int jj = r4 + 4 * k;
        tile[jj][c] = xtb[(size_t)(j0 + jj) * DD + d0 + c];
    }
    __syncthreads();
    #pragma unroll
    for (int k = 0; k < 16; ++k) {
        const int dd = r4 + 4 * k;
        xtT[(size_t)(d0 + dd) * NN + j0 + c] = tile[c][dd];
    }
}

// ---------------- Kernel 3: MFMA masked rank-1-score attention ----------------
// grid (NN/TI, S); block 256 = 4 waves. Each block: rows [i0,i0+32), j in
// [jbase, jbase+jlen). Writes fp32 partial numerators + lsum partials.
__global__ __launch_bounds__(256) void attn_kernel(
    const int* __restrict__ adj,
    const ushort_t* __restrict__ xtT,
    const float* __restrict__ wh1, const float* __restrict__ e1,
    const float* __restrict__ e1b,
    const float* __restrict__ wh2, const float* __restrict__ ey,
    const float* __restrict__ ez,
    float* __restrict__ pout, float* __restrict__ plsum, int jlen)
{
    __shared__ __align__(16) ushort_t xtT_lds[DD * LDP];   // 18432 B
    __shared__ __align__(16) ushort_t p_lds[TI * LDP];     //  4608 B
    __shared__ float s_wh1[TI], s_e1[TI], s_e1b[TI];

    const int t = threadIdx.x;
    const int i0 = blockIdx.x * TI;
    const int s  = blockIdx.y;
    const int jbase = s * jlen;
    const int lane = t & 63;
    const int w = t >> 6;            // wave 0..3
    const int l15 = lane & 15;
    const int quad = lane >> 4;
    const int ihalf = w & 1;         // which 16-row half this wave computes
    const int dgrp = w >> 1;         // which 64-col d-group this wave computes

    if (t < TI) {
        s_wh1[t] = wh1[i0 + t];
        s_e1[t]  = e1[i0 + t];
        s_e1b[t] = e1b[i0 + t];
    }

    float4_t acc[4];
    #pragma unroll
    for (int dt = 0; dt < 4; ++dt) acc[dt] = (float4_t)0.0f;
    float pls[8];
    #pragma unroll
    for (int k = 0; k < 8; ++k) pls[k] = 0.0f;

    for (int j0 = jbase; j0 < jbase + jlen; j0 += TJ) {
        __syncthreads();   // protect LDS vs previous iteration's phase C

        // ---- phase A: stage xtT tile [128 d][64 j] bf16 into LDS ----
        #pragma unroll
        for (int c = 0; c < 4; ++c) {
            const int idx = c * 256 + t;
            const int row = idx >> 3;        // d row 0..127
            const int ch  = idx & 7;         // 16-byte chunk 0..7
            const uint4 v = *(const uint4*)(xtT + (size_t)row * NN + j0 + ch * 8);
            *(uint4*)(&xtT_lds[row * LDP + ch * 8]) = v;
        }

        // ---- phase B: p tile (bf16) + register lsum partials ----
        {
            const float w2j = wh2[j0 + lane];
            const float eyj = ey[j0 + lane];
            const float ezj = ez[j0 + lane];
            const int* ap = adj + (size_t)(i0 + w * 8) * NN + j0 + lane;
            #pragma unroll
            for (int k = 0; k < 8; ++k) {
                const int il = w * 8 + k;
                const int av = ap[(size_t)k * NN];
                float p = 0.0f;
                if (av > 0) {
                    const bool cpos = (s_wh1[il] + w2j) > 0.0f;
                    p = cpos ? s_e1[il] * eyj : s_e1b[il] * ezj;
                }
                pls[k] += p;
                p_lds[il * LDP + lane] = f2bf(p);
            }
        }
        __syncthreads();

        // ---- phase C: MFMA. wave -> (ihalf, dgrp): C[16 i][64 d] ----
        #pragma unroll
        for (int kc = 0; kc < 2; ++kc) {
            const short8_t af = *(const short8_t*)(
                &p_lds[(ihalf * 16 + l15) * LDP + kc * 32 + quad * 8]);
            #pragma unroll
            for (int dt = 0; dt < 4; ++dt) {
                const short8_t bf = *(const short8_t*)(
                    &xtT_lds[((dgrp * 4 + dt) * 16 + l15) * LDP + kc * 32 + quad * 8]);
                acc[dt] = __builtin_amdgcn_mfma_f32_16x16x32_bf16(af, bf, acc[dt], 0, 0, 0);
            }
        }
    }

    // ---- lsum partial: reduce 64 lanes once, write ----
    #pragma unroll
    for (int k = 0; k < 8; ++k) {
        float v = pls[k];
        #pragma unroll
        for (int o = 1; o < 64; o <<= 1) v += __shfl_xor(v, o);
        if (lane == 0) plsum[(size_t)s * NN + i0 + w * 8 + k] = v;
    }

    // ---- store fp32 partial numerators ----
    #pragma unroll
    for (int dt = 0; dt < 4; ++dt) {
        const int d = (dgrp * 4 + dt) * 16 + l15;
        #pragma unroll
        for (int reg = 0; reg < 4; ++reg) {
            const int i = i0 + ihalf * 16 + quad * 4 + reg;
            pout[((size_t)s * NN + i) * DD + d] = acc[dt][reg];
        }
    }
}

// ---------------- Kernel 4: combine partials + normalize + expmap0 + proj ----
__global__ __launch_bounds__(128) void reduce_kernel(
    const float* __restrict__ pout, const float* __restrict__ plsum,
    float* __restrict__ out, int S)
{
    const int i = blockIdx.x;
    const int t = threadIdx.x;
    float v = 0.0f;
    for (int s = 0; s < S; ++s) v += pout[((size_t)s * NN + i) * DD + t];
    float ls = 0.0f;
    for (int s = 0; s < S; ++s) ls += plsum[(size_t)s * NN + i];
    v /= ls;
    float ss = v * v;
    #pragma unroll
    for (int o = 1; o < 64; o <<= 1) ss += __shfl_xor(ss, o);
    __shared__ float r2[2];
    if ((t & 63) == 0) r2[t >> 6] = ss;
    __syncthreads();
    const float total = r2[0] + r2[1];
    const float nraw = sqrtf(total);
    const float nv   = fmaxf(nraw, EPSF);
    const float th   = tanhf(nv);
    const float ysc  = th / nv;
    const float nyr  = ysc * nraw;
    const float ny   = fmaxf(nyr, EPSF);
    const float psc  = (ny > MAXNORM) ? (MAXNORM / ny) : 1.0f;
    const float os   = ysc * psc;
    out[(size_t)i * DD + t] = v * os;
}

extern "C" void kernel_launch(void* const* d_in, const int* in_sizes, int n_in,
                              void* d_out, int out_size, void* d_ws, size_t ws_size,
                              hipStream_t stream) {
    const float* x   = (const float*)d_in[0];
    const int*   adj = (const int*)d_in[1];
    const float* a   = (const float*)d_in[2];
    float* out = (float*)d_out;

    // ---- workspace layout ----
    char* ws = (char*)d_ws;
    ushort_t* xtb = (ushort_t*)ws;  ws += (size_t)NN * DD * sizeof(ushort_t);
    ushort_t* xtT = (ushort_t*)ws;  ws += (size_t)DD * NN * sizeof(ushort_t);
    float* wh1 = (float*)ws;        ws += NN * sizeof(float);
    float* wh2 = (float*)ws;        ws += NN * sizeof(float);
    float* e1  = (float*)ws;        ws += NN * sizeof(float);
    float* e1b = (float*)ws;        ws += NN * sizeof(float);
    float* eyv = (float*)ws;        ws += NN * sizeof(float);
    float* ezv = (float*)ws;        ws += NN * sizeof(float);

    const size_t fixed = (size_t)(ws - (char*)d_ws);
    const size_t perS  = (size_t)NN * DD * sizeof(float) + NN * sizeof(float);
    // S must divide 192 so jlen is a multiple of TJ=64.
    int S = 1;
    const int cand[5] = {8, 6, 4, 3, 2};
    for (int c = 0; c < 5; ++c) {
        if (fixed + (size_t)cand[c] * perS <= ws_size) { S = cand[c]; break; }
    }
    float* plsum = (float*)ws;      ws += (size_t)S * NN * sizeof(float);
    float* pout  = (float*)ws;

    const int jlen = NN / S;

    prep_kernel<<<NN, 128, 0, stream>>>(x, a, xtb, wh1, wh2, e1, e1b, eyv, ezv);
    transpose_kernel<<<dim3(NN / 64, DD / 64), 256, 0, stream>>>(xtb, xtT);
    attn_kernel<<<dim3(NN / TI, S), 256, 0, stream>>>(
        adj, xtT, wh1, e1, e1b, wh2, eyv, ezv, pout, plsum, jlen);
    reduce_kernel<<<NN, 128, 0, stream>>>(pout, plsum, out, S);
}